// Round 6
// baseline (245.798 us; speedup 1.0000x reference)
//
#include <hip/hip_runtime.h>

#define B_ 64
#define H_ 32
#define DN 512
#define DR 64
#define BS 128
#define TK 16             // keys per tile
#define MAXKV 4096
#define LOG2E 1.44269504088896340736f
#define SCALE_ (1.0f/24.0f)   // 1/sqrt(576)
#define NEG_INF -1e30f

typedef float    f32x4 __attribute__((ext_vector_type(4)));
typedef _Float16 f16x4 __attribute__((ext_vector_type(4)));

#define MFMA16 __builtin_amdgcn_mfma_f32_16x16x16f16

__device__ __forceinline__ f16x4 cvt4(f32x4 a) {
  f16x4 r;
  r[0] = (_Float16)a[0]; r[1] = (_Float16)a[1];
  r[2] = (_Float16)a[2]; r[3] = (_Float16)a[3];
  return r;
}

// LDS-only barrier: drains lgkm, leaves global_load_lds (vmcnt) in flight.
__device__ __forceinline__ void ldsbar() {
  asm volatile("s_waitcnt lgkmcnt(0)" ::: "memory");
  __builtin_amdgcn_sched_barrier(0);
  __builtin_amdgcn_s_barrier();
  __builtin_amdgcn_sched_barrier(0);
}

// Counted wait for the current tile's DMA (9 loads/wave/tile), then barrier.
__device__ __forceinline__ void wait_tile(bool next_in_flight) {
  if (next_in_flight) asm volatile("s_waitcnt vmcnt(9)" ::: "memory");
  else                asm volatile("s_waitcnt vmcnt(0)" ::: "memory");
  __builtin_amdgcn_sched_barrier(0);
  __builtin_amdgcn_s_barrier();
  __builtin_amdgcn_sched_barrier(0);
}

__device__ __forceinline__ void gl_lds16(const float* g, void* l) {
  __builtin_amdgcn_global_load_lds(
      (const __attribute__((address_space(1))) void*)g,
      (__attribute__((address_space(3))) void*)l, 16, 0, 0);
}

// Stage one 16-key tile (nope [16][512] f32 + rope [16][64] f32) into LDS.
// LDS dest is linear (base + lane*16); the XOR swizzle (slot ^= key&7, in
// 16B slots) is applied on the per-lane GLOBAL source; reads use the same
// XOR (involution). 9 gl_lds instructions per wave.
__device__ __forceinline__ void stage_tile(
    float* kb_lds, float* kr_lds,
    const float* kvn, const float* kvr,
    const size_t blkrow, const int w, const int lane)
{
  #pragma unroll
  for (int j = 0; j < 8; ++j) {
    const int I  = w * 8 + j;                 // 0..31
    const int kl = I >> 1;                    // key-local 0..15
    const int sp = ((I & 1) << 6) + lane;     // physical 16B slot 0..127
    const int s  = sp ^ (kl & 7);             // content slot
    gl_lds16(kvn + (blkrow + kl) * DN + s * 4, (char*)kb_lds + I * 1024);
  }
  {
    const int I  = w;                         // 0..3
    const int kl = I * 4 + (lane >> 4);       // key-local 0..15
    const int sp = lane & 15;
    const int s  = sp ^ (kl & 7);
    gl_lds16(kvr + (blkrow + kl) * DR + s * 4, (char*)kr_lds + I * 1024);
  }
}

// Kernel 1: per (b, chunk) flash-decode partial. 16-key tiles, 4 waves.
// Phase A: wave (wh, wd) computes S-partial[16 keys][16 heads] over half
// the 576 dims (18 MFMA); partials summed thread-parallel from LDS.
// PV: wave (hw, dv) computes [16 heads][256 dims] from swizzled K-LDS.
// LDS 80,640 B -> 2 blocks/CU (8 waves/CU).
__global__ __launch_bounds__(256, 2) void mla_chunk(
    const float* __restrict__ qn, const float* __restrict__ qr,
    const float* __restrict__ kvn, const float* __restrict__ kvr,
    const int* __restrict__ btab, const int* __restrict__ kseq,
    _Float16* __restrict__ po, float* __restrict__ ml,
    const int nc, const int chunk)
{
  // XCD swizzle: grid divisible by 8; consecutive bc share an XCD.
  const int raw = blockIdx.x;
  const int bc  = (raw & 7) * ((int)gridDim.x >> 3) + (raw >> 3);
  const int b = bc / nc, c = bc - b * nc;
  const int klen = kseq[b];
  const int kbase = c * chunk;
  if (kbase >= klen) return;
  const int nvalid = min(chunk, klen - kbase);
  const int nsb = (nvalid + TK - 1) / TK;

  const int tid = threadIdx.x;
  const int w = tid >> 6, l = tid & 63, l15 = l & 15, lg = l >> 4;
  const int kd = lg * 4;
  const int wh = w & 1, wd = w >> 1;     // phase-A roles (head half, dim half)
  const int hw = w & 1, dv = w >> 1;     // PV roles (head half, dim half)
  const int head = tid & 31, j0 = tid >> 5;   // softmax roles

  __shared__ float KB[2][TK][DN];        // 64 KB, swizzled
  __shared__ float KR[2][TK][DR];        // 8 KB, swizzled
  __shared__ float Spart[2][TK][H_];     // 4 KB: S dim-half partials
  __shared__ _Float16 Plds[H_][20];      // 1.25 KB
  __shared__ float Mred[4][H_], Lred[4][H_];
  __shared__ float Mnew_s[H_], fact_s[H_], Mrun[H_], Lrun[H_];

  if (tid < H_) { Mrun[tid] = NEG_INF; Lrun[tid] = 0.f; }

  f32x4 acc[16];
  #pragma unroll
  for (int i = 0; i < 16; ++i) acc[i] = (f32x4){0.f, 0.f, 0.f, 0.f};

  // ---- Q fragments in f16 registers (18 per wave: this wave's dim half) ----
  // B-frag: col = l15 -> head wh*16+l15, k = kd+i.
  f16x4 Qf[18];
  {
    const float* qn_ = qn + ((size_t)b * H_ + wh * 16 + l15) * DN;
    const float* qr_ = qr + ((size_t)b * H_ + wh * 16 + l15) * DR;
    if (wd == 0) {
      #pragma unroll
      for (int i = 0; i < 18; ++i)
        Qf[i] = cvt4(*(const f32x4*)(qn_ + i * 16 + kd));
    } else {
      #pragma unroll
      for (int i = 0; i < 14; ++i)
        Qf[i] = cvt4(*(const f32x4*)(qn_ + 288 + i * 16 + kd));
      #pragma unroll
      for (int i = 0; i < 4; ++i)
        Qf[14 + i] = cvt4(*(const f32x4*)(qr_ + i * 16 + kd));
    }
  }
  __builtin_amdgcn_sched_barrier(0);   // Qf loads fully retired before staging

  // ---- prologue: stage tiles 0 and 1 ----
  {
    const size_t br0 = (size_t)btab[b * 32 + (kbase >> 7)] * BS + (kbase & (BS - 1));
    stage_tile(&KB[0][0][0], &KR[0][0][0], kvn, kvr, br0, w, l);
    if (nsb > 1) {
      const int kb1 = kbase + TK;
      const size_t br1 = (size_t)btab[b * 32 + (kb1 >> 7)] * BS + (kb1 & (BS - 1));
      stage_tile(&KB[1][0][0], &KR[1][0][0], kvn, kvr, br1, w, l);
    }
  }
  __builtin_amdgcn_sched_barrier(0);

  for (int t = 0; t < nsb; ++t) {
    const int buf = t & 1;
    wait_tile(t + 1 < nsb);      // tile t landed; tile t+1 stays in flight

    // ---- Phase A: S-partial = K . Q^T over this wave's dim half ----
    const char* kA = (const char*)&KB[buf][0][0] + l15 * 2048;
    const char* rA = (const char*)&KR[buf][0][0] + l15 * 256;
    const int x7 = l15 & 7;
    f32x4 s0 = {0.f, 0.f, 0.f, 0.f};
    if (wd == 0) {
      #pragma unroll
      for (int d0 = 0; d0 < 18; ++d0) {
        f32x4 kv4 = *(const f32x4*)(kA + (((d0 * 4 + lg) ^ x7) << 4));
        s0 = MFMA16(cvt4(kv4), Qf[d0], s0, 0, 0, 0);
      }
    } else {
      #pragma unroll
      for (int d0 = 0; d0 < 14; ++d0) {
        f32x4 kv4 = *(const f32x4*)(kA + (((72 + d0 * 4 + lg) ^ x7) << 4));
        s0 = MFMA16(cvt4(kv4), Qf[d0], s0, 0, 0, 0);
      }
      #pragma unroll
      for (int d0 = 0; d0 < 4; ++d0) {
        f32x4 kv4 = *(const f32x4*)(rA + (((d0 * 4 + lg) ^ x7) << 4));
        s0 = MFMA16(cvt4(kv4), Qf[14 + d0], s0, 0, 0, 0);
      }
    }
    // D: row(key) = kd+r, col(head) = wh*16+l15
    #pragma unroll
    for (int r = 0; r < 4; ++r)
      Spart[wd][kd + r][wh * 16 + l15] = s0[r];
    ldsbar();

    // ---- softmax (thread-per-element): sum halves, scale, mask, max ----
    const int kb = kbase + t * TK;
    float sa = (Spart[0][j0][head] + Spart[1][j0][head]) * SCALE_;
    float sb = (Spart[0][j0 + 8][head] + Spart[1][j0 + 8][head]) * SCALE_;
    if (kb + j0 >= klen)     sa = NEG_INF;
    if (kb + j0 + 8 >= klen) sb = NEG_INF;
    float mp2 = fmaxf(sa, sb);
    mp2 = fmaxf(mp2, __shfl_xor(mp2, 32));
    if (l < 32) Mred[w][head] = mp2;
    ldsbar();

    if (tid < H_) {
      const float mprev = Mrun[tid];
      float mn = fmaxf(fmaxf(Mred[0][tid], Mred[1][tid]),
                       fmaxf(Mred[2][tid], Mred[3][tid]));
      mn = fmaxf(mn, mprev);
      Mnew_s[tid] = mn;
      fact_s[tid] = exp2f((mprev - mn) * LOG2E);
      Mrun[tid]   = mn;
    }
    ldsbar();

    // ---- P = exp(s - M) -> LDS (f16); l-partials; rescale acc ----
    {
      const float M = Mnew_s[head];
      const float pa = exp2f((sa - M) * LOG2E);
      const float pb = exp2f((sb - M) * LOG2E);
      Plds[head][j0]     = (_Float16)pa;
      Plds[head][j0 + 8] = (_Float16)pb;
      float lp = pa + pb;
      lp += __shfl_xor(lp, 32);
      if (l < 32) Lred[w][head] = lp;
    }
    #pragma unroll
    for (int r = 0; r < 4; ++r) {
      const float f = fact_s[hw * 16 + kd + r];
      #pragma unroll
      for (int dt = 0; dt < 16; ++dt) acc[dt][r] *= f;
    }
    ldsbar();

    // ---- running denominator ----
    if (tid < H_)
      Lrun[tid] = Lrun[tid] * fact_s[tid] +
                  (Lred[0][tid] + Lred[1][tid]) + (Lred[2][tid] + Lred[3][tid]);

    // ---- PV: wave (hw, dv) -> O[16 heads][256 dims], V from K-LDS ----
    {
      f16x4 pa4 = *(const f16x4*)&Plds[hw * 16 + l15][kd];
      const char* vB = (const char*)&KB[buf][0][0];
      #pragma unroll
      for (int dt = 0; dt < 16; ++dt) {
        const int cc = dv * 256 + dt * 16 + l15;
        f16x4 bv;
        #pragma unroll
        for (int i = 0; i < 4; ++i) {
          const int k2 = kd + i;
          const float x = *(const float*)(vB + k2 * 2048 +
              ((((cc >> 2) ^ (k2 & 7)) << 4) + ((cc & 3) << 2)));
          bv[i] = (_Float16)x;
        }
        acc[dt] = MFMA16(pa4, bv, acc[dt], 0, 0, 0);
      }
    }
    ldsbar();   // all reads of buf done block-wide

    // ---- stage tile t+2 into this buffer (stays in flight) ----
    if (t + 2 < nsb) {
      const int kb2 = kbase + (t + 2) * TK;
      const size_t br2 = (size_t)btab[b * 32 + (kb2 >> 7)] * BS + (kb2 & (BS - 1));
      stage_tile(&KB[buf][0][0], &KR[buf][0][0], kvn, kvr, br2, w, l);
    }
    __builtin_amdgcn_sched_barrier(0);
  }

  // ---- write partials: O (unnormalized, f16), m, l ----
  _Float16* pop = po + (size_t)(b * nc + c) * H_ * DN;
  #pragma unroll
  for (int dt = 0; dt < 16; ++dt)
    #pragma unroll
    for (int r = 0; r < 4; ++r)
      pop[(size_t)(hw * 16 + kd + r) * DN + dv * 256 + dt * 16 + l15] =
          (_Float16)acc[dt][r];
  if (tid < H_) {
    const size_t o = ((size_t)(b * nc + c) * H_ + tid) * 2;
    ml[o] = Mrun[tid]; ml[o + 1] = Lrun[tid];
  }
}

// Kernel 2: merge chunk partials per (b,h).
__global__ __launch_bounds__(256) void mla_reduce(
    const _Float16* __restrict__ po, const float* __restrict__ ml,
    const int* __restrict__ kseq, float* __restrict__ out,
    const int nc, const int chunk)
{
  const int bh = blockIdx.x;
  const int b = bh >> 5, h = bh & 31;
  const int klen = kseq[b];
  const int na = min(nc, (klen + chunk - 1) / chunk);
  const int tid = threadIdx.x;

  float M = NEG_INF;
  for (int c = 0; c < na; ++c)
    M = fmaxf(M, ml[((size_t)(b * nc + c) * H_ + h) * 2]);

  float s0 = 0.f, s1 = 0.f, den = 0.f;
  for (int c = 0; c < na; ++c) {
    const size_t o = ((size_t)(b * nc + c) * H_ + h) * 2;
    const float e = exp2f((ml[o] - M) * LOG2E);
    den += ml[o + 1] * e;
    const _Float16* p = po + ((size_t)(b * nc + c) * H_ + h) * DN;
    s0 += (float)p[tid] * e;
    s1 += (float)p[tid + 256] * e;
  }
  const float inv = 1.f / den;
  float* op = out + ((size_t)b * H_ + h) * DN;
  op[tid]       = s0 * inv;
  op[tid + 256] = s1 * inv;
}

extern "C" void kernel_launch(void* const* d_in, const int* in_sizes, int n_in,
                              void* d_out, int out_size, void* d_ws, size_t ws_size,
                              hipStream_t stream) {
  const float* qn  = (const float*)d_in[0];
  const float* qr  = (const float*)d_in[1];
  const float* kvn = (const float*)d_in[2];
  const float* kvr = (const float*)d_in[3];
  const int*  btab = (const int*)d_in[4];
  const int*  kseq = (const int*)d_in[6];
  float* out = (float*)d_out;

  // workspace-adaptive chunk count: nc chunks of 4096/nc keys
  int nc = 16;
  while (nc > 1 &&
         ((size_t)B_ * nc * H_ * DN * sizeof(_Float16) +
          (size_t)B_ * nc * H_ * 2 * sizeof(float)) > ws_size)
    nc >>= 1;
  const int chunk = MAXKV / nc;

  _Float16* po = (_Float16*)d_ws;                          // [B][nc][H][DN] f16
  float* ml = (float*)(po + (size_t)B_ * nc * H_ * DN);    // [B][nc][H][2]  f32

  mla_chunk<<<B_ * nc, 256, 0, stream>>>(qn, qr, kvn, kvr, btab, kseq,
                                         po, ml, nc, chunk);
  mla_reduce<<<B_ * H_, 256, 0, stream>>>(po, ml, kseq, out, nc, chunk);
}